// Round 2
// baseline (2819.597 us; speedup 1.0000x reference)
//
#include <hip/hip_runtime.h>
#include <hip/hip_bf16.h>

#define B_   128
#define T_   512
#define L_   8
#define E_   128
#define H_   512

// Partition: 4 batch-groups (32 rows each) x 16 WGs = 64 WGs, 256 thr each.
// WG (bg,g): batch rows [bg*32,+32), hidden units [g*32,+32) -> 128 gate rows.
// Wave wv = gate type; per wave N=32 (2 N-tiles), M=32 (2 M-tiles), K=640.
//
// SYNC: tagged-data handshake, no flags, no producer drain.
// h is stored as u32 = (bf16(h) << 16) | tag16 in 3 rotating buffers
// (step t -> buffer t%3, tag = t+1). Consumers poll the slab DIRECTLY:
// load quads, check embedded tags, retry missing quads with s_sleep backoff.
// Poll success == fill complete (data already in registers -> LDS).
// Producer: fire-and-forget sc1 stores; no vmcnt(0), no flag store.
// 3-buffer overwrite safety: buffer written at step t is only rewritten at
// t+3; the producer's t+3 store transitively requires TWO completed
// poll->store links across all same-bg WGs, each anchored by a data
// dependency (stored h values depend on the polled loads via the MFMA
// chain), so every consumer has read the old data before overwrite.
#define BG_   4
#define WPG_  16
#define JW_   32
#define HROW_ 512             // u32 per h row
#define HBUF_ (B_ * HROW_)    // u32 per buffer (65536)
#define GSTR  132             // gbuf row stride (floats)

typedef __attribute__((ext_vector_type(8))) short s8v;   // 8 bf16
typedef __attribute__((ext_vector_type(4))) float f4v;   // MFMA acc
typedef unsigned long long u64;
typedef unsigned int u32;

__device__ __forceinline__ float bf16u_to_f(unsigned short s) {
  union { unsigned u; float f; } c; c.u = ((unsigned)s) << 16; return c.f;
}
// LLC-coherent (sc1) accesses: bypass non-coherent per-XCD L2.
__device__ __forceinline__ u64 llc_load8(const void* p) {
  return __hip_atomic_load((const u64*)p, __ATOMIC_RELAXED, __HIP_MEMORY_SCOPE_AGENT);
}
__device__ __forceinline__ void llc_store8(void* p, u64 v) {
  __hip_atomic_store((u64*)p, v, __ATOMIC_RELAXED, __HIP_MEMORY_SCOPE_AGENT);
}
// Fast activations via v_exp_f32 + v_rcp_f32 (~1e-6 abs err)
__device__ __forceinline__ float sigf(float x) {
  return __builtin_amdgcn_rcpf(1.f + __expf(-x));
}
__device__ __forceinline__ float tanh_f(float x) {
  return 1.f - 2.f * __builtin_amdgcn_rcpf(1.f + __expf(2.f * x));
}

// ---------------------------------------------------------------------------
__global__ void embed_kernel(const int* __restrict__ tokens,
                             const float* __restrict__ values,
                             const float* __restrict__ emb,
                             __hip_bfloat16* __restrict__ x_bf) {
  int idx = blockIdx.x * blockDim.x + threadIdx.x;   // [0, B*T*E)
  int e  = idx & (E_ - 1);
  int bt = idx >> 7;
  int b  = bt >> 9;
  int t  = bt & (T_ - 1);
  const int*   tok = tokens + (size_t)bt * L_;
  const float* val = values + (size_t)bt * L_;
  float acc = 0.f;
#pragma unroll
  for (int l = 0; l < L_; ++l) acc += emb[(size_t)tok[l] * E_ + e] * val[l];
  acc = fmaxf(acc, 0.f);
  x_bf[((size_t)t * B_ + b) * E_ + e] = __float2bfloat16(acc);
}

// ---------------------------------------------------------------------------
// out[b,t] = W_out . h_t + b_out from the LDS-staged (xor-swizzled) slab.
__device__ __forceinline__ void out_dot_lds(const u64* __restrict__ h_lds,
                                            int t, int bg,
                                            const float* __restrict__ wout_s,
                                            float bout, float* __restrict__ out) {
  const int um = threadIdx.x >> 3;
  const int uj = threadIdx.x & 7;
  const u64* row = h_lds + (size_t)um * 128;
  const float* wr = wout_s + uj * 64;
  float p = 0.f;
#pragma unroll
  for (int j = 0; j < 8; ++j) {
    int pc = ((uj * 8 + j) ^ (um & 7)) * 2;
    u64 qa = row[pc], qb = row[pc + 1];
    p += bf16u_to_f((unsigned short)(qa      )) * wr[j * 8 + 0];
    p += bf16u_to_f((unsigned short)(qa >> 16)) * wr[j * 8 + 1];
    p += bf16u_to_f((unsigned short)(qa >> 32)) * wr[j * 8 + 2];
    p += bf16u_to_f((unsigned short)(qa >> 48)) * wr[j * 8 + 3];
    p += bf16u_to_f((unsigned short)(qb      )) * wr[j * 8 + 4];
    p += bf16u_to_f((unsigned short)(qb >> 16)) * wr[j * 8 + 5];
    p += bf16u_to_f((unsigned short)(qb >> 32)) * wr[j * 8 + 6];
    p += bf16u_to_f((unsigned short)(qb >> 48)) * wr[j * 8 + 7];
  }
  p += __shfl_down(p, 4, 8);
  p += __shfl_down(p, 2, 8);
  p += __shfl_down(p, 1, 8);
  if (uj == 0) out[(size_t)(bg * 32 + um) * T_ + t] = p + bout;
}

// ---------------------------------------------------------------------------
// Tagged poll+fill: loads the WG's 32x512 tagged-u32 slab row-interleaved
// (thread (um,fc): quads qi = fc+8*jj), checks tags (u64-granular: tag lives
// in the low u32 of every u64), packs valid quads to bf16 u64s and ds_writes
// them into the xor-swizzled h_lds layout. Retries ONLY missing quads with
// s_sleep backoff. Contains the h_lds-protect barrier (entry) and the exit
// vote barrier.
__device__ __forceinline__ void poll_fill(u64* __restrict__ h_lds,
                                          const u32* __restrict__ src_row,
                                          u32 want, int um, int fc) {
  u64 lo[16], hi[16];
#pragma unroll
  for (int jj = 0; jj < 16; ++jj) {          // issue before barrier: RT overlaps it
    const u32* q = src_row + (size_t)(fc + 8 * jj) * 4;
    lo[jj] = llc_load8(q);
    hi[jj] = llc_load8(q + 2);
  }
  __syncthreads();   // prior h_lds readers (MFMA A-reads, out_dot) done
  unsigned miss = 0xffffu;
  for (;;) {
#pragma unroll
    for (int jj = 0; jj < 16; ++jj) if (miss & (1u << jj)) {
      u32 a0 = (u32)lo[jj], a1 = (u32)(lo[jj] >> 32);
      u32 a2 = (u32)hi[jj], a3 = (u32)(hi[jj] >> 32);
      if ((((a0 ^ want) | (a2 ^ want)) & 0xffffu) == 0u) {
        u64 pk = (u64)((a0 >> 16) | (a1 & 0xffff0000u))
               | ((u64)((a2 >> 16) | (a3 & 0xffff0000u)) << 32);
        int qi = fc + 8 * jj;
        int pc = ((qi >> 1) ^ (um & 7)) * 2 + (qi & 1);
        h_lds[(size_t)um * 128 + pc] = pk;
        miss &= ~(1u << jj);
      }
    }
    if (__syncthreads_and((int)(miss == 0u))) break;
    __builtin_amdgcn_s_sleep(2);
#pragma unroll
    for (int jj = 0; jj < 16; ++jj) if (miss & (1u << jj)) {
      const u32* q = src_row + (size_t)(fc + 8 * jj) * 4;
      lo[jj] = llc_load8(q);
      hi[jj] = llc_load8(q + 2);
    }
  }
}

// ---------------------------------------------------------------------------
__global__ void __launch_bounds__(256, 1)
lstm_kernel(const float* __restrict__ W_ih, const float* __restrict__ W_hh,
            const float* __restrict__ b_ih, const float* __restrict__ b_hh,
            const float* __restrict__ W_out, const float* __restrict__ b_out,
            const __hip_bfloat16* __restrict__ x_bf,
            u32* __restrict__ h_base,             // 3 * B*H tagged u32 (zeroed)
            float* __restrict__ out) {            // B*T f32
  __shared__ __align__(16) u64   h_lds[32 * 128];  // 32 rows x 64 16B chunks, xor-swizzled
  __shared__ __align__(16) float gbuf[32][GSTR];   // gates staging
  __shared__ __align__(16) float bias_s[128];
  __shared__ float wout_s[H_];

  const int tid = threadIdx.x;
  const int wg  = blockIdx.x;
  const int bg  = wg >> 4;            // 0..3
  const int g   = wg & (WPG_ - 1);    // 0..15
  const int j0g = g * JW_;

  const int wv   = tid >> 6;          // wave = gate type 0..3
  const int lane = tid & 63;
  const int m16  = lane & 15;
  const int q    = lane >> 4;
  const int sw   = m16 & 7;           // xor-swizzle key

  // ---- one-time: W fragments -> registers (B operand, 2 N-tiles x 20 K) --
  s8v bfrag[2][20];
#pragma unroll
  for (int nt = 0; nt < 2; ++nt) {
    const int r = wv * H_ + j0g + nt * 16 + m16;        // global gate row
    const float* wih_r = W_ih + (size_t)r * E_;
    const float* whh_r = W_hh + (size_t)r * H_;
#pragma unroll
    for (int ks = 0; ks < 20; ++ks) {
      s8v v;
#pragma unroll
      for (int i = 0; i < 8; ++i) {
        int k = ks * 32 + q * 8 + i;
        float w = (k < E_) ? wih_r[k] : whh_r[k - E_];
        __hip_bfloat16 hb = __float2bfloat16(w);
        v[i] = *(short*)&hb;
      }
      bfrag[nt][ks] = v;
    }
  }
  if (tid < 128) {
    int gt = tid >> 5, jl = tid & 31;
    int r = gt * H_ + j0g + jl;
    bias_s[tid] = b_ih[r] + b_hh[r];
  }
  if (g == 0) for (int i = tid; i < H_; i += 256) wout_s[i] = W_out[i];

  // ---- per-step identities ----------------------------------------------
  const int um = tid >> 3;            // update/out/fill row
  const int jb = (tid & 7) * 4;       // update: 4 hidden units
  const int ub = bg * 32 + um;
  const int fc = tid & 7;             // fill: quad base
  float cst[4] = {0.f, 0.f, 0.f, 0.f};
  const float bout = b_out[0];

  int rp = 2, wp = 0;                 // h_{-1}=zeros (tag 0) in buf2; h_t -> buf t%3
  f4v acc[2][2];

  // prologue: x-part of step 0
  {
    const __hip_bfloat16* ax0 = x_bf + (size_t)(bg * 32 + m16) * E_ + q * 8;
    const __hip_bfloat16* ax1 = x_bf + (size_t)(bg * 32 + 16 + m16) * E_ + q * 8;
    f4v z = {0.f, 0.f, 0.f, 0.f};
    acc[0][0] = z; acc[0][1] = z; acc[1][0] = z; acc[1][1] = z;
#pragma unroll
    for (int ks = 0; ks < 4; ++ks) {
      s8v a0 = *(const s8v*)(ax0 + ks * 32);
      s8v a1 = *(const s8v*)(ax1 + ks * 32);
#pragma unroll
      for (int nt = 0; nt < 2; ++nt) {
        acc[0][nt] = __builtin_amdgcn_mfma_f32_16x16x32_bf16(a0, bfrag[nt][ks], acc[0][nt], 0, 0, 0);
        acc[1][nt] = __builtin_amdgcn_mfma_f32_16x16x32_bf16(a1, bfrag[nt][ks], acc[1][nt], 0, 0, 0);
      }
    }
  }

  for (int t = 0; t < T_; ++t) {
    const u32* h_prev = h_base + (size_t)rp * HBUF_;   // holds h_{t-1}, tag t
    u32*       h_next = h_base + (size_t)wp * HBUF_;   // gets h_t, tag t+1

    // ---- tagged poll+fill: h_{t-1} slab -> LDS (includes both barriers) --
    poll_fill(h_lds, h_prev + (size_t)ub * HROW_, (u32)t, um, fc);

    // ---- h-part MFMAs (K=512 from LDS; B from registers) ----------------
    {
      const u64* al0 = h_lds + (size_t)m16 * 128;
      const u64* al1 = h_lds + (size_t)(16 + m16) * 128;
#pragma unroll
      for (int ks4 = 0; ks4 < 16; ++ks4) {
        int pc = ((ks4 * 4 + q) ^ sw) * 2;
        s8v a0 = *(const s8v*)(al0 + pc);
        s8v a1 = *(const s8v*)(al1 + pc);
#pragma unroll
        for (int nt = 0; nt < 2; ++nt) {
          acc[0][nt] = __builtin_amdgcn_mfma_f32_16x16x32_bf16(a0, bfrag[nt][4 + ks4], acc[0][nt], 0, 0, 0);
          acc[1][nt] = __builtin_amdgcn_mfma_f32_16x16x32_bf16(a1, bfrag[nt][4 + ks4], acc[1][nt], 0, 0, 0);
        }
      }
    }

    // ---- stage gates to LDS (D: row=quad*4+r, col=m16) ------------------
#pragma unroll
    for (int mt = 0; mt < 2; ++mt)
#pragma unroll
      for (int nt = 0; nt < 2; ++nt)
#pragma unroll
        for (int r = 0; r < 4; ++r)
          gbuf[mt * 16 + q * 4 + r][wv * 32 + nt * 16 + m16] = acc[mt][nt][r];
    __syncthreads();   // gates ready

    // ---- CRITICAL PATH: pointwise -> tagged h stores (fire-and-forget) --
    {
      const float* gr = &gbuf[0][0] + (size_t)um * GSTR;
      f4v vi = *(const f4v*)(gr + jb);
      f4v vf = *(const f4v*)(gr + 32 + jb);
      f4v vg = *(const f4v*)(gr + 64 + jb);
      f4v vo = *(const f4v*)(gr + 96 + jb);
      f4v bi = *(const f4v*)(bias_s + jb);
      f4v bf = *(const f4v*)(bias_s + 32 + jb);
      f4v bgc = *(const f4v*)(bias_s + 64 + jb);
      f4v bo = *(const f4v*)(bias_s + 96 + jb);
      const u32 tagv = (u32)(t + 1) & 0xffffu;
      u32 w[4];
#pragma unroll
      for (int qq = 0; qq < 4; ++qq) {
        float si = sigf(vi[qq] + bi[qq]);
        float sf = sigf(vf[qq] + bf[qq]);
        float tg = tanh_f(vg[qq] + bgc[qq]);
        float so = sigf(vo[qq] + bo[qq]);
        cst[qq] = sf * cst[qq] + si * tg;
        float h = so * tanh_f(cst[qq]);
        __hip_bfloat16 hb = __float2bfloat16(h);
        w[qq] = ((u32)(*(unsigned short*)&hb) << 16) | ((qq & 1) ? 0u : tagv);
      }
      u32* dst = h_next + (size_t)ub * HROW_ + (j0g + jb);
      llc_store8(dst,     (u64)w[0] | ((u64)w[1] << 32));
      llc_store8(dst + 2, (u64)w[2] | ((u64)w[3] << 32));
      // NO drain, NO flag: consumers validate via embedded tags.
    }

    // ---- poll-shadow work (other WGs are polling) -----------------------
    if (g == 0 && t > 0)               // h_{t-1} still staged in LDS
      out_dot_lds(h_lds, t - 1, bg, wout_s, bout, out);

    if (t + 1 < T_) {                  // x-part of step t+1
      const __hip_bfloat16* xt = x_bf + (size_t)(t + 1) * B_ * E_;
      const __hip_bfloat16* ax0 = xt + (size_t)(bg * 32 + m16) * E_ + q * 8;
      const __hip_bfloat16* ax1 = xt + (size_t)(bg * 32 + 16 + m16) * E_ + q * 8;
      f4v z = {0.f, 0.f, 0.f, 0.f};
      acc[0][0] = z; acc[0][1] = z; acc[1][0] = z; acc[1][1] = z;
#pragma unroll
      for (int ks = 0; ks < 4; ++ks) {
        s8v a0 = *(const s8v*)(ax0 + ks * 32);
        s8v a1 = *(const s8v*)(ax1 + ks * 32);
#pragma unroll
        for (int nt = 0; nt < 2; ++nt) {
          acc[0][nt] = __builtin_amdgcn_mfma_f32_16x16x32_bf16(a0, bfrag[nt][ks], acc[0][nt], 0, 0, 0);
          acc[1][nt] = __builtin_amdgcn_mfma_f32_16x16x32_bf16(a1, bfrag[nt][ks], acc[1][nt], 0, 0, 0);
        }
      }
    }
    // no tail sync: poll_fill's entry barrier protects h_lds/gbuf reuse

    rp = wp; wp = (wp == 2) ? 0 : wp + 1;
  }

  // final output row: one more tagged fill of h_{T-1} (buf rp, tag T), LDS dot.
  if (g == 0) {
    poll_fill(h_lds, h_base + (size_t)rp * HBUF_ + (size_t)ub * HROW_,
              (u32)T_, um, fc);
    out_dot_lds(h_lds, T_ - 1, bg, wout_s, bout, out);
  }
}

// ---------------------------------------------------------------------------
extern "C" void kernel_launch(void* const* d_in, const int* in_sizes, int n_in,
                              void* d_out, int out_size, void* d_ws, size_t ws_size,
                              hipStream_t stream) {
  const int*   tokens = (const int*)d_in[0];
  const float* values = (const float*)d_in[1];
  const float* emb    = (const float*)d_in[2];
  const float* W_ih   = (const float*)d_in[3];
  const float* W_hh   = (const float*)d_in[4];
  const float* b_ih   = (const float*)d_in[5];
  const float* b_hh   = (const float*)d_in[6];
  const float* W_out  = (const float*)d_in[7];
  const float* b_out  = (const float*)d_in[8];
  float* out = (float*)d_out;

  char* ws = (char*)d_ws;
  __hip_bfloat16* x_bf = (__hip_bfloat16*)ws;                         // 16 MB
  u32* h_base = (u32*)(ws + (size_t)T_ * B_ * E_ * 2);                // 3 * 256KB tagged

  // zeroed buffers: h_{-1} = 0 with tag 0 (== tag expected at t=0)
  hipMemsetAsync(h_base, 0, (size_t)3 * HBUF_ * sizeof(u32), stream);

  embed_kernel<<<(B_ * T_ * E_) / 256, 256, 0, stream>>>(tokens, values, emb, x_bf);

  lstm_kernel<<<dim3(BG_ * WPG_), dim3(256), 0, stream>>>(
      W_ih, W_hh, b_ih, b_hh, W_out, b_out, x_bf, h_base, out);
}

// Round 5
// 2072.537 us; speedup vs baseline: 1.3605x; 1.3605x over previous
//
#include <hip/hip_runtime.h>
#include <hip/hip_bf16.h>

#define B_   128
#define T_   512
#define L_   8
#define E_   128
#define H_   512

// Partition: 8 batch-groups (16 rows each) x 16 WGs = 128 WGs, 256 thr each.
// gid = blockIdx % 8 -> under round-robin block->XCD dispatch, all 16 WGs of
// a group land on ONE XCD (verified by an xcc vote; numeric s_getreg, no
// symbolic hwreg). Fast path: group h/flag exchange via MUBUF buffer ops
// with sc0 (served by the XCD's coherent L2, ~200cy RT). Slow path: the
// R0-proven agent-scope (sc1) LLC protocol.
//
// HANG-PROOF DESIGN: producers DUAL-PUBLISH h and flags every step (sc0 copy
// into the fast area + sc1 copy into the slow area; counted vmcnt(1) lets
// the fast flag publish after only the L2 ack). Consumers poll fast flags
// with a BOUNDED spin; on timeout they permanently fall back to sc1 flags +
// sc1 h. Any mix of fast/slow consumers is correct because producers always
// serve both. No unbounded spin exists on the fast path.
#define NG_   8
#define WPG_  16
#define JW_   32
#define GSTR  132
#define HBUFB 131072                 // bytes per h buffer (128 rows x 1024B)
#define BARSA_OFF (3 * HBUFB)        // fast flags offset within fast area
#define FAST_BYTES (BARSA_OFF + NG_ * 64 * 4)
#define SPIN_MAX 4096                // bounded fast poll (~0.7ms worst case)

typedef __attribute__((ext_vector_type(8))) short s8v;      // 8 bf16
typedef __attribute__((ext_vector_type(4))) float f4v;      // MFMA acc
typedef __attribute__((ext_vector_type(4))) unsigned int u32x4;
typedef unsigned long long u64;
typedef unsigned int u32;

__device__ __forceinline__ float bf16u_to_f(unsigned short s) {
  union { unsigned u; float f; } c; c.u = ((unsigned)s) << 16; return c.f;
}
// Agent-scope (sc1) accesses: LLC-coherent, bypass non-coherent per-XCD L2.
__device__ __forceinline__ u64 llc_load8(const void* p) {
  return __hip_atomic_load((const u64*)p, __ATOMIC_RELAXED, __HIP_MEMORY_SCOPE_AGENT);
}
__device__ __forceinline__ unsigned llc_load4(const unsigned* p) {
  return __hip_atomic_load(p, __ATOMIC_RELAXED, __HIP_MEMORY_SCOPE_AGENT);
}
__device__ __forceinline__ void llc_store4(unsigned* p, unsigned v) {
  __hip_atomic_store(p, v, __ATOMIC_RELAXED, __HIP_MEMORY_SCOPE_AGENT);
}
// Fast activations via v_exp_f32 + v_rcp_f32 (~1e-6 abs err)
__device__ __forceinline__ float sigf(float x) {
  return __builtin_amdgcn_rcpf(1.f + __expf(-x));
}
__device__ __forceinline__ float tanh_f(float x) {
  return 1.f - 2.f * __builtin_amdgcn_rcpf(1.f + __expf(2.f * x));
}

// MUBUF sc0 ops (documented gfx950 cache flag for buffer_*). SRD covers the
// fast area; voffset = byte offset.
__device__ __forceinline__ void buf_store_sc0(u32x4 srd, unsigned voff, unsigned v) {
  asm volatile("buffer_store_dword %0, %1, %2, 0 offen sc0"
               :: "v"(v), "v"(voff), "s"(srd) : "memory");
}
__device__ __forceinline__ unsigned buf_load_sc0(u32x4 srd, unsigned voff) {
  unsigned v;
  asm volatile("buffer_load_dword %0, %1, %2, 0 offen sc0\n\ts_waitcnt vmcnt(0)"
               : "=v"(v) : "v"(voff), "s"(srd) : "memory");
  return v;
}

// Wave-0-only polls. Fast: bounded spin; returns false on timeout.
__device__ __forceinline__ bool wait_flags_fast(u32x4 srd, unsigned polloff, unsigned tgt) {
  for (int it = 0; it < SPIN_MAX; ++it) {
    unsigned v = buf_load_sc0(srd, polloff);
    if (__all((int)(v >= tgt))) return true;
    __builtin_amdgcn_s_sleep(1);
  }
  return false;
}
__device__ __forceinline__ void wait_flags_slow(const u32* flags, unsigned tgt) {
  const u32* p = flags + (threadIdx.x & 63);
  while (!__all((int)(llc_load4(p) >= tgt))) __builtin_amdgcn_s_sleep(1);
}

// ---------------------------------------------------------------------------
__global__ void embed_kernel(const int* __restrict__ tokens,
                             const float* __restrict__ values,
                             const float* __restrict__ emb,
                             __hip_bfloat16* __restrict__ x_bf) {
  int idx = blockIdx.x * blockDim.x + threadIdx.x;   // [0, B*T*E)
  int e  = idx & (E_ - 1);
  int bt = idx >> 7;
  int b  = bt >> 9;
  int t  = bt & (T_ - 1);
  const int*   tok = tokens + (size_t)bt * L_;
  const float* val = values + (size_t)bt * L_;
  float acc = 0.f;
#pragma unroll
  for (int l = 0; l < L_; ++l) acc += emb[(size_t)tok[l] * E_ + e] * val[l];
  acc = fmaxf(acc, 0.f);
  x_bf[((size_t)t * B_ + b) * E_ + e] = __float2bfloat16(acc);
}

// ---------------------------------------------------------------------------
// Fill: h_{t-1} group slab (16 rows x 512 bf16 = 16KB) -> LDS, xor-swizzled.
// Thread tid covers 64B contiguous of row tid>>4. fast: 4x buffer dwordx4
// sc0 + one vmcnt(0). slow: 8x agent u64 loads.
__device__ __forceinline__ void fill_slab(u32x4* __restrict__ h_lds4, int mode,
                                          u32x4 srd, unsigned voffA,
                                          const u64* __restrict__ slow_src,
                                          int tid) {
  u32x4 c0, c1, c2, c3;
  if (mode == 0) {
    asm volatile(
        "buffer_load_dwordx4 %0, %4, %5, 0 offen sc0\n\t"
        "buffer_load_dwordx4 %1, %4, %5, 0 offen offset:16 sc0\n\t"
        "buffer_load_dwordx4 %2, %4, %5, 0 offen offset:32 sc0\n\t"
        "buffer_load_dwordx4 %3, %4, %5, 0 offen offset:48 sc0\n\t"
        "s_waitcnt vmcnt(0)"
        : "=&v"(c0), "=&v"(c1), "=&v"(c2), "=&v"(c3)
        : "v"(voffA), "s"(srd) : "memory");
  } else {
    u64 a, b;
    a = llc_load8(slow_src + 0); b = llc_load8(slow_src + 1);
    c0 = (u32x4){(u32)a, (u32)(a >> 32), (u32)b, (u32)(b >> 32)};
    a = llc_load8(slow_src + 2); b = llc_load8(slow_src + 3);
    c1 = (u32x4){(u32)a, (u32)(a >> 32), (u32)b, (u32)(b >> 32)};
    a = llc_load8(slow_src + 4); b = llc_load8(slow_src + 5);
    c2 = (u32x4){(u32)a, (u32)(a >> 32), (u32)b, (u32)(b >> 32)};
    a = llc_load8(slow_src + 6); b = llc_load8(slow_src + 7);
    c3 = (u32x4){(u32)a, (u32)(a >> 32), (u32)b, (u32)(b >> 32)};
  }
  const int row = tid >> 4;           // 0..15
  const int sw2 = row & 7;
  const int cb  = (tid & 15) * 4;     // 16B-chunk base within row
  u32x4* dst = h_lds4 + (size_t)row * 64;
  dst[(cb + 0) ^ sw2] = c0;
  dst[(cb + 1) ^ sw2] = c1;
  dst[(cb + 2) ^ sw2] = c2;
  dst[(cb + 3) ^ sw2] = c3;
}

// ---------------------------------------------------------------------------
// out[b,t] = W_out . h_t + b_out from the LDS-staged (xor-swizzled) slab.
__device__ __forceinline__ void out_dot_lds16(const u32x4* __restrict__ h_lds4,
                                              int t, int gid,
                                              const float* __restrict__ wout_s,
                                              float bout, float* __restrict__ out) {
  const int um = threadIdx.x >> 4;
  const int uj = threadIdx.x & 15;
  const u64* row = (const u64*)(h_lds4 + (size_t)um * 64);
  const float* wr = wout_s + uj * 32;
  float p = 0.f;
#pragma unroll
  for (int j = 0; j < 4; ++j) {
    int pc = ((uj * 4 + j) ^ (um & 7)) * 2;
    u64 qa = row[pc], qb = row[pc + 1];
    p += bf16u_to_f((unsigned short)(qa      )) * wr[j * 8 + 0];
    p += bf16u_to_f((unsigned short)(qa >> 16)) * wr[j * 8 + 1];
    p += bf16u_to_f((unsigned short)(qa >> 32)) * wr[j * 8 + 2];
    p += bf16u_to_f((unsigned short)(qa >> 48)) * wr[j * 8 + 3];
    p += bf16u_to_f((unsigned short)(qb      )) * wr[j * 8 + 4];
    p += bf16u_to_f((unsigned short)(qb >> 16)) * wr[j * 8 + 5];
    p += bf16u_to_f((unsigned short)(qb >> 32)) * wr[j * 8 + 6];
    p += bf16u_to_f((unsigned short)(qb >> 48)) * wr[j * 8 + 7];
  }
  p += __shfl_down(p, 8, 16);
  p += __shfl_down(p, 4, 16);
  p += __shfl_down(p, 2, 16);
  p += __shfl_down(p, 1, 16);
  if (uj == 0) out[(size_t)(gid * 16 + um) * T_ + t] = p + bout;
}

// ---------------------------------------------------------------------------
__global__ void __launch_bounds__(256, 1)
lstm_kernel(const float* __restrict__ W_ih, const float* __restrict__ W_hh,
            const float* __restrict__ b_ih, const float* __restrict__ b_hh,
            const float* __restrict__ W_out, const float* __restrict__ b_out,
            const __hip_bfloat16* __restrict__ x_bf,
            u64* __restrict__ h_slow,             // 3 * B*H bf16 (zeroed), sc1 copies
            float* __restrict__ out,              // B*T f32
            u32* __restrict__ barsB,              // NG_ x 64 sc1 flags (zeroed)
            u32* __restrict__ xcc_tab,            // 128 slots (zeroed)
            char* __restrict__ fastbase) {        // sc0 area: 3 h bufs + flags (zeroed)
  __shared__ __align__(16) u32x4 h_lds4[16 * 64];  // 16 rows x 64 16B chunks
  __shared__ __align__(16) float gbuf[16][GSTR];   // gates staging
  __shared__ __align__(16) float bias_s[128];
  __shared__ float wout_s[H_];
  __shared__ int   cnt_same_s, bad_grp_s, mode_s;

  const int tid = threadIdx.x;
  const int wg  = blockIdx.x;
  const int gid = wg & (NG_ - 1);     // 0..7  (XCD under round-robin)
  const int g   = wg >> 3;            // 0..15
  const int j0g = g * JW_;

  const int wv   = tid >> 6;          // wave = gate type 0..3
  const int lane = tid & 63;
  const int m16  = lane & 15;
  const int q    = lane >> 4;
  const int sw   = m16 & 7;           // xor-swizzle key

  // SRD over the fast area (num_records=0xFFFFFFFF disables bounds check).
  u32x4 srd;
  {
    unsigned long long ba = (unsigned long long)fastbase;
    srd = (u32x4){(u32)ba, (u32)(ba >> 32) & 0xffffu, 0xffffffffu, 0x00020000u};
  }

  // ---- XCD-placement vote (one-time, agent scope; oracle-failure-safe) ---
  // HW_REG_XCC_ID: hwreg id 20, offset 0, size 4 -> imm = 20 | ((4-1)<<11).
  const unsigned xcc = (unsigned)__builtin_amdgcn_s_getreg(20 | (3 << 11));
  if (tid == 0) { cnt_same_s = 0; bad_grp_s = 0; llc_store4(xcc_tab + wg, xcc + 1u); }
  __syncthreads();
  if (tid < 128) {
    const u32* slot = xcc_tab + tid;
    unsigned v = llc_load4(slot);
    while (v == 0u) { __builtin_amdgcn_s_sleep(8); v = llc_load4(slot); }
    if (v == xcc + 1u) atomicAdd(&cnt_same_s, 1);
    else if ((tid & 7) == gid) bad_grp_s = 1;   // a group member is elsewhere
  }
  __syncthreads();
  // fast iff all group members share my XCD and the chip-wide same-xcc count
  // is physically plausible (<=64; a constant-oracle yields 128 -> slow).
  if (tid == 0) mode_s = ((bad_grp_s == 0) && (cnt_same_s <= 64)) ? 0 : 1;

  // ---- one-time: W fragments -> registers (B operand, 2 N-tiles x 20 K) --
  s8v bfrag[2][20];
#pragma unroll
  for (int nt = 0; nt < 2; ++nt) {
    const int r = wv * H_ + j0g + nt * 16 + m16;        // global gate row
    const float* wih_r = W_ih + (size_t)r * E_;
    const float* whh_r = W_hh + (size_t)r * H_;
#pragma unroll
    for (int ks = 0; ks < 20; ++ks) {
      s8v v;
#pragma unroll
      for (int i = 0; i < 8; ++i) {
        int k = ks * 32 + q * 8 + i;
        float w = (k < E_) ? wih_r[k] : whh_r[k - E_];
        __hip_bfloat16 hb = __float2bfloat16(w);
        v[i] = *(short*)&hb;
      }
      bfrag[nt][ks] = v;
    }
  }
  if (tid < 128) {
    int gt = tid >> 5, jl = tid & 31;
    int r = gt * H_ + j0g + jl;
    bias_s[tid] = b_ih[r] + b_hh[r];
  }
  if (g == 0) for (int i = tid; i < H_; i += 256) wout_s[i] = W_out[i];

  // ---- per-step identities ----------------------------------------------
  const int um = tid >> 4;            // update/fill/out row (0..15)
  const int jb = (tid & 15) * 2;      // update: 2 hidden units
  const int ub = gid * 16 + um;       // global batch row
  float cst[2] = {0.f, 0.f};
  const float bout = b_out[0];
  u32* h_slow32 = (u32*)h_slow;
  u32* flagsB   = barsB + gid * 64;
  u32* myflagB  = flagsB + (g << 2) + wv;
  const unsigned hoffA_base  = (unsigned)(ub * 1024 + (g * 16 + (tid & 15)) * 4);
  const unsigned hslow_base  = (unsigned)(ub * 256 + g * 16 + (tid & 15));
  const unsigned flagAoff    = (unsigned)(BARSA_OFF + (gid * 64 + (g << 2) + wv) * 4);
  const unsigned polloff     = (unsigned)(BARSA_OFF + (gid * 64 + (tid & 63)) * 4);
  const unsigned filloffA    = (unsigned)((gid * 16 + (tid >> 4)) * 1024 + (tid & 15) * 64);
  const unsigned slab_u64off = (unsigned)(gid * 16 * 128 + tid * 8);

  int rp = 2, wp = 0;                 // h_{-1}=zeros in buf2; h_t -> buf t%3
  f4v acc[2];

  // prologue: x-part of step 0 (M=16: single A-tile)
  {
    const __hip_bfloat16* ax0 = x_bf + (size_t)(gid * 16 + m16) * E_ + q * 8;
    f4v z = {0.f, 0.f, 0.f, 0.f};
    acc[0] = z; acc[1] = z;
#pragma unroll
    for (int ks = 0; ks < 4; ++ks) {
      s8v a0 = *(const s8v*)(ax0 + ks * 32);
#pragma unroll
      for (int nt = 0; nt < 2; ++nt)
        acc[nt] = __builtin_amdgcn_mfma_f32_16x16x32_bf16(a0, bfrag[nt][ks], acc[nt], 0, 0, 0);
    }
  }
  __syncthreads();   // bias/wout/mode_s ready

  for (int t = 0; t < T_; ++t) {
    // ---- wave 0 waits for step t-1 producers (fast w/ bounded fallback) -
    if (wv == 0) {
      int m0 = mode_s;
      bool got = false;
      if (m0 == 0) {
        got = wait_flags_fast(srd, polloff, (unsigned)t);
        if (!got && lane == 0) mode_s = 1;   // permanent fallback
      }
      if (!got) wait_flags_slow(flagsB, (unsigned)t);
    }
    __syncthreads();   // release; also orders shadow h_lds reads before fill
    const int mode = mode_s;

    // ---- cooperative fill: h_{t-1} group slab -> LDS --------------------
    fill_slab(h_lds4, mode, srd, (unsigned)(rp * HBUFB) + filloffA,
              h_slow + (size_t)rp * 16384 + slab_u64off, tid);
    __syncthreads();   // fill complete

    // ---- h-part MFMAs (K=512 from LDS; B from registers) ----------------
    {
      const s8v* arow = (const s8v*)(h_lds4 + (size_t)m16 * 64);
#pragma unroll
      for (int ks4 = 0; ks4 < 16; ++ks4) {
        s8v a0 = arow[(ks4 * 4 + q) ^ sw];
#pragma unroll
        for (int nt = 0; nt < 2; ++nt)
          acc[nt] = __builtin_amdgcn_mfma_f32_16x16x32_bf16(a0, bfrag[nt][4 + ks4], acc[nt], 0, 0, 0);
      }
    }

    // ---- stage gates to LDS (D: row=quad*4+r, col=m16) ------------------
#pragma unroll
    for (int nt = 0; nt < 2; ++nt)
#pragma unroll
      for (int r = 0; r < 4; ++r)
        gbuf[q * 4 + r][wv * 32 + nt * 16 + m16] = acc[nt][r];
    __syncthreads();   // gates ready

    // ---- CRITICAL PATH: pointwise -> dual h store -> counted drains -----
    {
      const float* gr = &gbuf[um][0];
      float si0 = sigf(gr[jb]      + bias_s[jb]);
      float si1 = sigf(gr[jb + 1]  + bias_s[jb + 1]);
      float sf0 = sigf(gr[32 + jb] + bias_s[32 + jb]);
      float sf1 = sigf(gr[33 + jb] + bias_s[33 + jb]);
      float tg0 = tanh_f(gr[64 + jb] + bias_s[64 + jb]);
      float tg1 = tanh_f(gr[65 + jb] + bias_s[65 + jb]);
      float so0 = sigf(gr[96 + jb] + bias_s[96 + jb]);
      float so1 = sigf(gr[97 + jb] + bias_s[97 + jb]);
      cst[0] = sf0 * cst[0] + si0 * tg0;
      cst[1] = sf1 * cst[1] + si1 * tg1;
      float h0 = so0 * tanh_f(cst[0]);
      float h1 = so1 * tanh_f(cst[1]);
      __hip_bfloat16 hb0 = __float2bfloat16(h0);
      __hip_bfloat16 hb1 = __float2bfloat16(h1);
      u32 w = (u32)(*(unsigned short*)&hb0) | ((u32)(*(unsigned short*)&hb1) << 16);
      // op1: fast copy (sc0, acked at local L2)
      buf_store_sc0(srd, (unsigned)(wp * HBUFB) + hoffA_base, w);
      // op2: slow copy (sc1, acked at LLC)
      llc_store4(h_slow32 + (size_t)wp * 32768 + hslow_base, w);
      // fast flag after op1 only (op2 is the single newest outstanding op)
      asm volatile("s_waitcnt vmcnt(1)" ::: "memory");
      if (lane == 0) buf_store_sc0(srd, flagAoff, (unsigned)(t + 1));
      // slow flag after everything (incl. op2) is acked at LLC
      asm volatile("s_waitcnt vmcnt(0)" ::: "memory");
      if (lane == 0) llc_store4(myflagB, (unsigned)(t + 1));
    }

    // ---- poll-shadow work (other WGs are polling/filling) ---------------
    if (g == 0 && t > 0)               // h_{t-1} still staged in LDS
      out_dot_lds16(h_lds4, t - 1, gid, wout_s, bout, out);

    if (t + 1 < T_) {                  // x-part of step t+1
      const __hip_bfloat16* xt = x_bf + (size_t)(t + 1) * B_ * E_;
      const __hip_bfloat16* ax0 = xt + (size_t)(gid * 16 + m16) * E_ + q * 8;
      f4v z = {0.f, 0.f, 0.f, 0.f};
      acc[0] = z; acc[1] = z;
#pragma unroll
      for (int ks = 0; ks < 4; ++ks) {
        s8v a0 = *(const s8v*)(ax0 + ks * 32);
#pragma unroll
        for (int nt = 0; nt < 2; ++nt)
          acc[nt] = __builtin_amdgcn_mfma_f32_16x16x32_bf16(a0, bfrag[nt][ks], acc[nt], 0, 0, 0);
      }
    }
    // no tail sync: the loop-head barrier protects h_lds/gbuf reuse

    rp = wp; wp = (wp == 2) ? 0 : wp + 1;
  }

  // final output row: wait for step T-1, fill h_{T-1} slab, LDS dot.
  if (g == 0) {
    if (wv == 0) {
      int m0 = mode_s;
      bool got = false;
      if (m0 == 0) {
        got = wait_flags_fast(srd, polloff, (unsigned)T_);
        if (!got && lane == 0) mode_s = 1;
      }
      if (!got) wait_flags_slow(flagsB, (unsigned)T_);
    }
    __syncthreads();   // also orders last out_dot_lds reads before refill
    fill_slab(h_lds4, mode_s, srd, (unsigned)(rp * HBUFB) + filloffA,
              h_slow + (size_t)rp * 16384 + slab_u64off, tid);
    __syncthreads();
    out_dot_lds16(h_lds4, T_ - 1, gid, wout_s, bout, out);
  }
}

// ---------------------------------------------------------------------------
extern "C" void kernel_launch(void* const* d_in, const int* in_sizes, int n_in,
                              void* d_out, int out_size, void* d_ws, size_t ws_size,
                              hipStream_t stream) {
  const int*   tokens = (const int*)d_in[0];
  const float* values = (const float*)d_in[1];
  const float* emb    = (const float*)d_in[2];
  const float* W_ih   = (const float*)d_in[3];
  const float* W_hh   = (const float*)d_in[4];
  const float* b_ih   = (const float*)d_in[5];
  const float* b_hh   = (const float*)d_in[6];
  const float* W_out  = (const float*)d_in[7];
  const float* b_out  = (const float*)d_in[8];
  float* out = (float*)d_out;

  char* ws = (char*)d_ws;
  __hip_bfloat16* x_bf = (__hip_bfloat16*)ws;                  // 16 MB
  char* p = ws + (size_t)T_ * B_ * E_ * 2;
  u64*  h_slow  = (u64*)p;                                     // 3 x 128 KB (sc1)
  u32*  barsB   = (u32*)(p + 3 * HBUFB);                       // 2 KB
  u32*  xcc_tab = (u32*)(p + 3 * HBUFB + 2048);                // 512 B
  char* fastbase = p + 3 * HBUFB + 2048 + 512;                 // 384 KB + 2 KB (sc0)

  // zero slow bufs + flags + vote table + fast bufs + fast flags (contiguous)
  hipMemsetAsync(p, 0, (size_t)(3 * HBUFB + 2048 + 512) + FAST_BYTES, stream);

  embed_kernel<<<(B_ * T_ * E_) / 256, 256, 0, stream>>>(tokens, values, emb, x_bf);

  lstm_kernel<<<dim3(NG_ * WPG_), dim3(256), 0, stream>>>(
      W_ih, W_hh, b_ih, b_hh, W_out, b_out, x_bf, h_slow, out, barsB, xcc_tab,
      fastbase);
}